// Round 8
// baseline (204.130 us; speedup 1.0000x reference)
//
#include <hip/hip_runtime.h>
#include <hip/hip_bf16.h>
#include <math.h>

typedef unsigned short ush;
typedef __attribute__((ext_vector_type(8))) _Float16 fragh;  // 8 fp16 = 4 VGPRs
typedef __attribute__((ext_vector_type(4))) _Float16 half4;
typedef __attribute__((ext_vector_type(4))) float f32x4;

#define S_   1024
#define H_   1024
#define NH_  16
#define D_   64
#define L_   9
#define MB_  (1048576ull)

// async global->LDS, 16B per lane; lds ptr must be wave-uniform base.
__device__ __forceinline__ void load_lds16(const ush* g, const ush* l) {
  __builtin_amdgcn_global_load_lds(
      (const __attribute__((address_space(1))) void*)g,
      (__attribute__((address_space(3))) void*)l, 16, 0, 0);
}

// ---------------------------------------------------------------------------
// Cast + transpose 4 weights in one launch. W [k][n] fp32 -> WT [n][k] fp16.
// Grid (16,16,4). (verified R7)
// ---------------------------------------------------------------------------
__global__ __launch_bounds__(256) void cast_wT4(
    const float* W0, const float* W1, const float* W2, const float* W3,
    ush* T0, ush* T1, ush* T2, ush* T3) {
  __shared__ __align__(16) float Ls[64][68];
  const float* W = (blockIdx.z == 0) ? W0 : (blockIdx.z == 1) ? W1
                 : (blockIdx.z == 2) ? W2 : W3;
  ush* Th = (blockIdx.z == 0) ? T0 : (blockIdx.z == 1) ? T1
          : (blockIdx.z == 2) ? T2 : T3;
  const int tid = threadIdx.x;
  const int n0 = blockIdx.x * 64, k0 = blockIdx.y * 64;
#pragma unroll
  for (int it = 0; it < 4; it++) {
    int flat = tid + 256 * it;
    int row = flat >> 4, nc = (flat & 15) * 4;
    *(float4*)&Ls[row][nc] = *(const float4*)&W[(size_t)(k0 + row) * 1024 + n0 + nc];
  }
  __syncthreads();
#pragma unroll
  for (int it = 0; it < 2; it++) {
    int flat = tid + 256 * it;
    int nrow = flat >> 3, kc = (flat & 7) * 8;
    fragh v;
#pragma unroll
    for (int u = 0; u < 8; u++) v[u] = (_Float16)Ls[kc + u][nrow];
    *(fragh*)&Th[(size_t)(n0 + nrow) * 1024 + k0 + kc] = v;
  }
}

// ---------------------------------------------------------------------------
// Cast x: fp32 [4096x1024] -> fp16. Grid 2048.
// ---------------------------------------------------------------------------
__global__ __launch_bounds__(256) void cast_x(
    const float* __restrict__ x, ush* __restrict__ xh) {
  const size_t i = ((size_t)blockIdx.x * 256 + threadIdx.x) * 8;
  float4 a = *(const float4*)&x[i];
  float4 b = *(const float4*)&x[i + 4];
  fragh v;
  v[0] = (_Float16)a.x; v[1] = (_Float16)a.y;
  v[2] = (_Float16)a.z; v[3] = (_Float16)a.w;
  v[4] = (_Float16)b.x; v[5] = (_Float16)b.y;
  v[6] = (_Float16)b.z; v[7] = (_Float16)b.w;
  *(fragh*)&xh[i] = v;
}

// ---------------------------------------------------------------------------
// Fused QKV GEMM, fp16 single-term, 128(M) x 64(N) tile for TLP: grid
// (16,32,3) = 1536 blocks = 6/CU (LDS 24KB, ~56 VGPR). R7's 128x128 ran
// 3/CU with all pipes <25% busy -- latency-bound at the barrier drain;
// doubling resident blocks lets other blocks' MFMAs cover each drain.
// Per wave per K-step: 8 MFMA / 6 ds_read_b128 / 3 stage-calls.
// z in {0,1,2} -> {Wq->qh, Wk->kh, Wv->vT transposed}.
// ---------------------------------------------------------------------------
__global__ __launch_bounds__(256) void gemm_qkv(
    const ush* __restrict__ xh,
    const ush* __restrict__ Bq, const ush* __restrict__ Bk,
    const ush* __restrict__ Bv,
    const float* __restrict__ bq, const float* __restrict__ bk,
    const float* __restrict__ bv,
    ush* __restrict__ qh, ush* __restrict__ kh, ush* __restrict__ vT) {
  __shared__ __align__(16) ush As[2][128][32];   // [buf][m][k] fp16 bits
  __shared__ __align__(16) ush Bs[2][64][32];    // [buf][n][k] fp16 bits
  const int tid = threadIdx.x, lane = tid & 63, wave = tid >> 6;
  const int l15 = lane & 15, quad = lane >> 4;
  const int m0 = blockIdx.y * 128, n0 = blockIdx.x * 64;
  const int z = blockIdx.z;
  const ush* Bg = (z == 0) ? Bq : (z == 1) ? Bk : Bv;
  const float* bias = (z == 0) ? bq : (z == 1) ? bk : bv;
  ush* outp = (z == 0) ? qh : (z == 1) ? kh : vT;

  const int wm = (wave >> 1) * 64, wn = (wave & 1) * 32;

  f32x4 acc[4][2];
#pragma unroll
  for (int i = 0; i < 4; i++)
#pragma unroll
    for (int j = 0; j < 2; j++) acc[i][j] = (f32x4){0.f, 0.f, 0.f, 0.f};

  auto stage = [&](int bi, int k0) {
#pragma unroll
    for (int jj = 0; jj < 2; jj++) {          // A: 8 KB = 8 wave-calls
      const int call = wave * 2 + jj;
      const int c = call * 64 + lane;         // chunk in [0,512)
      const int r = c >> 2, ch = c & 3;
      load_lds16(xh + (size_t)(m0 + r) * 1024 + k0 + ch * 8,
                 &As[bi][0][0] + (size_t)call * 512);
    }
    {                                          // B: 4 KB = 4 wave-calls
      const int c = wave * 64 + lane;          // chunk in [0,256)
      const int r = c >> 2, ch = c & 3;
      load_lds16(Bg + (size_t)(n0 + r) * 1024 + k0 + ch * 8,
                 &Bs[bi][0][0] + (size_t)wave * 512);
    }
  };

  stage(0, 0);
  __syncthreads();

  for (int k0 = 0; k0 < 1024; k0 += 32) {
    const int cur = (k0 >> 5) & 1;
    if (k0 + 32 < 1024) stage(cur ^ 1, k0 + 32);

    fragh a[4], b[2];
#pragma unroll
    for (int s = 0; s < 4; s++)
      a[s] = *(const fragh*)&As[cur][wm + s * 16 + l15][quad * 8];
#pragma unroll
    for (int t = 0; t < 2; t++)
      b[t] = *(const fragh*)&Bs[cur][wn + t * 16 + l15][quad * 8];
#pragma unroll
    for (int mi = 0; mi < 4; mi++)
#pragma unroll
      for (int ni = 0; ni < 2; ni++)
        acc[mi][ni] = __builtin_amdgcn_mfma_f32_16x16x32_f16(
            a[mi], b[ni], acc[mi][ni], 0, 0, 0);
    __syncthreads();
  }

#pragma unroll
  for (int mi = 0; mi < 4; mi++) {
    const int rbase = m0 + wm + mi * 16 + quad * 4;
    const int bb = rbase >> 10, ss = rbase & 1023;
#pragma unroll
    for (int ni = 0; ni < 2; ni++) {
      const int col = n0 + wn + ni * 16 + l15;
      const float bv_ = bias[col];
      const int hidx = col >> 6, d = col & 63;
      if (z == 2) {
        // V: direct-transposed vT [bh][d][s], 4 consecutive s packed
        half4 p4;
        p4[0] = (_Float16)(acc[mi][ni][0] + bv_);
        p4[1] = (_Float16)(acc[mi][ni][1] + bv_);
        p4[2] = (_Float16)(acc[mi][ni][2] + bv_);
        p4[3] = (_Float16)(acc[mi][ni][3] + bv_);
        *(half4*)&outp[((size_t)(bb * NH_ + hidx) * D_ + d) * S_ + ss] = p4;
      } else {
#pragma unroll
        for (int r = 0; r < 4; r++) {
          const size_t o =
              ((size_t)(bb * NH_ + hidx) * S_ + (ss + r)) * D_ + d;
          *(_Float16*)&outp[o] = (_Float16)(acc[mi][ni][r] + bv_);
        }
      }
    }
  }
}

// ---------------------------------------------------------------------------
// O-projection GEMM: fp16 single-term. 128x64 tile; fp32 out + bias +
// residual. LDS 24KB. Grid (16,32) = 512 = 2/CU. (verified R7)
// ---------------------------------------------------------------------------
__global__ __launch_bounds__(256) void gemm_o(
    const ush* __restrict__ ctxh, const ush* __restrict__ Bo,
    const float* __restrict__ bo, const float* __restrict__ resid,
    float* __restrict__ outf) {
  __shared__ __align__(16) ush As[2][128][32];   // [buf][m][k]
  __shared__ __align__(16) ush Bs[2][64][32];    // [buf][n][k]
  const int tid = threadIdx.x, lane = tid & 63, wave = tid >> 6;
  const int l15 = lane & 15, quad = lane >> 4;
  const int m0 = blockIdx.y * 128, n0 = blockIdx.x * 64;
  const int wm = (wave >> 1) * 64, wn = (wave & 1) * 32;

  f32x4 acc[4][2];
#pragma unroll
  for (int i = 0; i < 4; i++)
#pragma unroll
    for (int j = 0; j < 2; j++) acc[i][j] = (f32x4){0.f, 0.f, 0.f, 0.f};

  auto stage = [&](int bi, int k0) {
#pragma unroll
    for (int jj = 0; jj < 2; jj++) {          // A: 8 wave-calls
      const int call = wave * 2 + jj;
      const int c = call * 64 + lane;
      const int r = c >> 2, ch = c & 3;
      load_lds16(ctxh + (size_t)(m0 + r) * 1024 + k0 + ch * 8,
                 &As[bi][0][0] + (size_t)call * 512);
    }
    {                                          // B: 4 wave-calls (1/wave)
      const int c = wave * 64 + lane;          // chunk in [0,256)
      const int r = c >> 2, ch = c & 3;
      load_lds16(Bo + (size_t)(n0 + r) * 1024 + k0 + ch * 8,
                 &Bs[bi][0][0] + (size_t)wave * 512);
    }
  };

  stage(0, 0);
  __syncthreads();

  for (int k0 = 0; k0 < 1024; k0 += 32) {
    const int cur = (k0 >> 5) & 1;
    if (k0 + 32 < 1024) stage(cur ^ 1, k0 + 32);

    fragh a[4], b[2];
#pragma unroll
    for (int s = 0; s < 4; s++)
      a[s] = *(const fragh*)&As[cur][wm + s * 16 + l15][quad * 8];
#pragma unroll
    for (int t = 0; t < 2; t++)
      b[t] = *(const fragh*)&Bs[cur][wn + t * 16 + l15][quad * 8];
#pragma unroll
    for (int mi = 0; mi < 4; mi++)
#pragma unroll
      for (int ni = 0; ni < 2; ni++)
        acc[mi][ni] = __builtin_amdgcn_mfma_f32_16x16x32_f16(
            a[mi], b[ni], acc[mi][ni], 0, 0, 0);
    __syncthreads();
  }

#pragma unroll
  for (int mi = 0; mi < 4; mi++) {
    const int rbase = m0 + wm + mi * 16 + quad * 4;
#pragma unroll
    for (int ni = 0; ni < 2; ni++) {
      const int col = n0 + wn + ni * 16 + l15;
      const float bv_ = bo[col];
#pragma unroll
      for (int r = 0; r < 4; r++) {
        const int m = rbase + r;
        outf[(size_t)m * 1024 + col] =
            acc[mi][ni][r] + bv_ + resid[(size_t)m * 1024 + col];
      }
    }
  }
}

// ---------------------------------------------------------------------------
// MFMA flash attention, fp16 (verified R7): window |j0-q0| <= 128, LDS-LUT
// softmax with fixed shift M=2, fp16 P/ctx. LDS ~28KB -> 4 blocks/CU.
// ---------------------------------------------------------------------------
__global__ __launch_bounds__(256) void attn2(
    const ush* __restrict__ qh, const ush* __restrict__ kh,
    const ush* __restrict__ vT, ush* __restrict__ ch) {
  __shared__ __align__(16) ush Kh[64][72];
  __shared__ __align__(16) ush VTs[64][72];   // [d][j]
  __shared__ __align__(16) ush Pst[64][72];   // [m][j]
  __shared__ float LUT[256];
  const int tid = threadIdx.x;
  const int lane = tid & 63, wave = tid >> 6;
  const int l15 = lane & 15, quad = lane >> 4;
  const int w16 = wave * 16;
  const int bh = blockIdx.y;
  const int b = bh >> 4, h = bh & 15;
  const int q0 = blockIdx.x * 64;

  const float K1 = 0.18033688011112042f;   // 0.125 * log2(e)
  const float K2 = 0.14426950408889634f;   // 0.1   * log2(e)
  {
    const float dd = (float)tid;
    LUT[tid] = __expf(-0.1f * fminf(dd, 5.0f)) * K1 - dd * K2
             - 2.8853900817779268f;        // 2*log2(e): fixed shift M=2
  }

  const size_t qrow = ((size_t)bh * S_ + q0 + w16 + l15) * D_;
  fragh a_h[2];
  a_h[0] = *(const fragh*)&qh[qrow + quad * 8];
  a_h[1] = *(const fragh*)&qh[qrow + 32 + quad * 8];

  f32x4 o[4];
  float lrow[4];
#pragma unroll
  for (int i = 0; i < 4; i++) {
    o[i] = (f32x4){0.f, 0.f, 0.f, 0.f};
    lrow[i] = 0.f;
  }

  const size_t kbase = (size_t)bh * S_ * D_;
  const size_t vbase = (size_t)bh * D_ * S_;

  const int jlo = (q0 > 128) ? q0 - 128 : 0;
  const int jend = (q0 + 192 < S_) ? q0 + 192 : S_;

  for (int j0 = jlo; j0 < jend; j0 += 64) {
    __syncthreads();   // prior tile's frag reads done (also fences LUT)
#pragma unroll
    for (int it = 0; it < 2; it++) {
      const int flat = tid + 256 * it;
      const int row = flat >> 3, dc = (flat & 7) * 8;
      *(uint4*)&Kh[row][dc] =
          *(const uint4*)&kh[kbase + (size_t)(j0 + row) * D_ + dc];
      *(uint4*)&VTs[row][dc] =
          *(const uint4*)&vT[vbase + (size_t)row * S_ + j0 + dc];
    }
    __syncthreads();

    // ---- S = Q.K^T (single fp16 term) ----
    f32x4 c4[4];
#pragma unroll
    for (int nt = 0; nt < 4; nt++) c4[nt] = (f32x4){0.f, 0.f, 0.f, 0.f};
#pragma unroll
    for (int kk = 0; kk < 2; kk++) {
#pragma unroll
      for (int nt = 0; nt < 4; nt++) {
        fragh bh_ = *(const fragh*)&Kh[nt * 16 + l15][kk * 32 + quad * 8];
        c4[nt] = __builtin_amdgcn_mfma_f32_16x16x32_f16(a_h[kk], bh_, c4[nt], 0, 0, 0);
      }
    }

    // ---- LUT softmax + P store (C-layout: row=quad*4+r) ----
    const int ib = q0 + w16 + quad * 4 - j0 - l15;
#pragma unroll
    for (int r = 0; r < 4; r++) {
#pragma unroll
      for (int nt = 0; nt < 4; nt++) {
        int di = ib + r - nt * 16;
        di = (di < 0) ? -di : di;
        const float sv = exp2f(fmaf(c4[nt][r], K1, LUT[di]));
        lrow[r] += sv;
        *(_Float16*)&Pst[w16 + quad * 4 + r][nt * 16 + l15] = (_Float16)sv;
      }
    }

    // ---- PV (own rows only; same-wave LDS ordering, no barrier) ----
    fragh pa[2];
    pa[0] = *(const fragh*)&Pst[w16 + l15][quad * 8];
    pa[1] = *(const fragh*)&Pst[w16 + l15][32 + quad * 8];
#pragma unroll
    for (int dt = 0; dt < 4; dt++) {
      fragh vb0 = *(const fragh*)&VTs[dt * 16 + l15][quad * 8];
      fragh vb1 = *(const fragh*)&VTs[dt * 16 + l15][32 + quad * 8];
      o[dt] = __builtin_amdgcn_mfma_f32_16x16x32_f16(pa[0], vb0, o[dt], 0, 0, 0);
      o[dt] = __builtin_amdgcn_mfma_f32_16x16x32_f16(pa[1], vb1, o[dt], 0, 0, 0);
    }
  }

  // ---- deferred row-sum reduction + normalize + write fp16 ctx ----
#pragma unroll
  for (int r = 0; r < 4; r++) {
#pragma unroll
    for (int off = 1; off < 16; off <<= 1) lrow[r] += __shfl_xor(lrow[r], off);
    const float inv = 1.0f / lrow[r];
    const size_t rowp =
        ((size_t)(b * S_ + q0 + w16 + quad * 4 + r)) * H_ + h * 64;
#pragma unroll
    for (int dt = 0; dt < 4; dt++)
      *(_Float16*)&ch[rowp + dt * 16 + l15] = (_Float16)(o[dt][r] * inv);
  }
}

// ---------------------------------------------------------------------------
// Fused LayerNorm + span logits: one block per row. (verified R10)
// ---------------------------------------------------------------------------
__global__ __launch_bounds__(256) void ln_span(
    const float* __restrict__ y, const float* __restrict__ g,
    const float* __restrict__ bta, const float* __restrict__ Wsp,
    const float* __restrict__ bs, float* __restrict__ logits) {
  const int row = blockIdx.x;
  const int tid = threadIdx.x, lane = tid & 63, wave = tid >> 6;
  const float* yr = y + (size_t)row * 1024;
  float vals[4], s = 0.f, s2 = 0.f;
#pragma unroll
  for (int i = 0; i < 4; i++) {
    float t = yr[tid + i * 256];
    vals[i] = t; s += t; s2 += t * t;
  }
#pragma unroll
  for (int off = 32; off; off >>= 1) {
    s += __shfl_xor(s, off);
    s2 += __shfl_xor(s2, off);
  }
  __shared__ float red[8];
  __shared__ float red9[4][12];
  if (lane == 0) { red[wave] = s; red[4 + wave] = s2; }
  __syncthreads();
  s = red[0] + red[1] + red[2] + red[3];
  s2 = red[4] + red[5] + red[6] + red[7];
  const float mu = s * (1.0f / 1024.0f);
  const float var = s2 * (1.0f / 1024.0f) - mu * mu;
  const float inv = rsqrtf(var + 1e-5f);

  float lg[9];
#pragma unroll
  for (int l = 0; l < 9; l++) lg[l] = 0.f;
#pragma unroll
  for (int i = 0; i < 4; i++) {
    const int hh = tid + i * 256;
    const float yn = (vals[i] - mu) * inv * g[hh] + bta[hh];
#pragma unroll
    for (int l = 0; l < 9; l++) lg[l] += yn * Wsp[hh * 9 + l];
  }
#pragma unroll
  for (int l = 0; l < 9; l++) {
#pragma unroll
    for (int off = 32; off; off >>= 1) lg[l] += __shfl_xor(lg[l], off);
  }
  if (lane == 0) {
#pragma unroll
    for (int l = 0; l < 9; l++) red9[wave][l] = lg[l];
  }
  __syncthreads();
  if (tid < 9) {
    logits[(size_t)row * 9 + tid] =
        red9[0][tid] + red9[1][tid] + red9[2][tid] + red9[3][tid] + bs[tid];
  }
}

// ---------------------------------------------------------------------------
// Entity-bias adjustment + FP32 output. One thread per token.
// ---------------------------------------------------------------------------
__global__ __launch_bounds__(256) void final_kernel(
    const float* __restrict__ logits, const float* __restrict__ eb,
    float* __restrict__ out) {
  const int m = blockIdx.x * 256 + threadIdx.x;
  const int i = m & 1023;
  float cur[9];
#pragma unroll
  for (int l = 0; l < 9; l++) cur[l] = logits[(size_t)m * 9 + l];
  if (i > 0) {
    const float* prev = logits + (size_t)(m - 1) * 9;
    int am = 0;
    float best = prev[0];
#pragma unroll
    for (int l = 1; l < 9; l++) {
      float pv = prev[l];
      if (pv > best) { best = pv; am = l; }
    }
    if (am == 1) cur[2] += 2.0f * eb[2];
  }
#pragma unroll
  for (int l = 0; l < 9; l++) out[(size_t)m * 9 + l] = cur[l];
}

// ---------------------------------------------------------------------------
extern "C" void kernel_launch(void* const* d_in, const int* in_sizes, int n_in,
                              void* d_out, int out_size, void* d_ws, size_t ws_size,
                              hipStream_t stream) {
  const float* x    = (const float*)d_in[0];
  const float* Wq   = (const float*)d_in[1];
  const float* bq   = (const float*)d_in[2];
  const float* Wk   = (const float*)d_in[3];
  const float* bk   = (const float*)d_in[4];
  const float* Wv   = (const float*)d_in[5];
  const float* bv   = (const float*)d_in[6];
  const float* Wo   = (const float*)d_in[7];
  const float* bo   = (const float*)d_in[8];
  const float* ln_g = (const float*)d_in[9];
  const float* ln_b = (const float*)d_in[10];
  const float* Ws   = (const float*)d_in[11];
  const float* bs   = (const float*)d_in[12];
  const float* eb   = (const float*)d_in[13];
  float* out = (float*)d_out;
  char* W8 = (char*)d_ws;

  // ---- ws layout (fp16 everywhere; 64 MB envelope) ----
  ush* WoT  = (ush*)(W8 + 0 * MB_);
  ush* WqT  = (ush*)(W8 + 2 * MB_);
  ush* WkT  = (ush*)(W8 + 4 * MB_);
  ush* WvT  = (ush*)(W8 + 6 * MB_);
  ush* xh   = (ush*)(W8 + 8 * MB_);
  ush* qh   = (ush*)(W8 + 16 * MB_);
  ush* kh   = (ush*)(W8 + 24 * MB_);
  ush* vT   = (ush*)(W8 + 32 * MB_);
  ush* ctxh = (ush*)(W8 + 40 * MB_);
  float* y_ws  = (float*)(W8 + 48 * MB_);
  float* lg_ws = (float*)(W8 + 16 * MB_);  // over qh (dead after attn)

  cast_wT4<<<dim3(16, 16, 4), 256, 0, stream>>>(
      Wq, Wk, Wv, Wo, WqT, WkT, WvT, WoT);
  cast_x<<<2048, 256, 0, stream>>>(x, xh);

  // Q+K+V fused: 1536 blocks = 6/CU, 24KB LDS.
  gemm_qkv<<<dim3(16, 32, 3), 256, 0, stream>>>(
      xh, WqT, WkT, WvT, bq, bk, bv, qh, kh, vT);
  attn2<<<dim3(16, 64), 256, 0, stream>>>(qh, kh, vT, ctxh);
  gemm_o<<<dim3(16, 32), 256, 0, stream>>>(ctxh, WoT, bo, x, y_ws);
  ln_span<<<4096, 256, 0, stream>>>(y_ws, ln_g, ln_b, Ws, bs, lg_ws);
  final_kernel<<<16, 256, 0, stream>>>(lg_ws, eb, out);
}

// Round 9
// 203.000 us; speedup vs baseline: 1.0056x; 1.0056x over previous
//
#include <hip/hip_runtime.h>
#include <hip/hip_bf16.h>
#include <math.h>

typedef unsigned short ush;
typedef __attribute__((ext_vector_type(8))) _Float16 fragh;  // 8 fp16 = 4 VGPRs
typedef __attribute__((ext_vector_type(4))) _Float16 half4;
typedef __attribute__((ext_vector_type(4))) float f32x4;

#define S_   1024
#define H_   1024
#define NH_  16
#define D_   64
#define L_   9
#define MB_  (1048576ull)

// async global->LDS, 16B per lane; lds ptr must be wave-uniform base.
__device__ __forceinline__ void load_lds16(const ush* g, const ush* l) {
  __builtin_amdgcn_global_load_lds(
      (const __attribute__((address_space(1))) void*)g,
      (__attribute__((address_space(3))) void*)l, 16, 0, 0);
}

// ---------------------------------------------------------------------------
// Cast + transpose 4 weights in one launch. W [k][n] fp32 -> WT [n][k] fp16.
// Grid (16,16,4). (verified R7)
// ---------------------------------------------------------------------------
__global__ __launch_bounds__(256) void cast_wT4(
    const float* W0, const float* W1, const float* W2, const float* W3,
    ush* T0, ush* T1, ush* T2, ush* T3) {
  __shared__ __align__(16) float Ls[64][68];
  const float* W = (blockIdx.z == 0) ? W0 : (blockIdx.z == 1) ? W1
                 : (blockIdx.z == 2) ? W2 : W3;
  ush* Th = (blockIdx.z == 0) ? T0 : (blockIdx.z == 1) ? T1
          : (blockIdx.z == 2) ? T2 : T3;
  const int tid = threadIdx.x;
  const int n0 = blockIdx.x * 64, k0 = blockIdx.y * 64;
#pragma unroll
  for (int it = 0; it < 4; it++) {
    int flat = tid + 256 * it;
    int row = flat >> 4, nc = (flat & 15) * 4;
    *(float4*)&Ls[row][nc] = *(const float4*)&W[(size_t)(k0 + row) * 1024 + n0 + nc];
  }
  __syncthreads();
#pragma unroll
  for (int it = 0; it < 2; it++) {
    int flat = tid + 256 * it;
    int nrow = flat >> 3, kc = (flat & 7) * 8;
    fragh v;
#pragma unroll
    for (int u = 0; u < 8; u++) v[u] = (_Float16)Ls[kc + u][nrow];
    *(fragh*)&Th[(size_t)(n0 + nrow) * 1024 + k0 + kc] = v;
  }
}

// ---------------------------------------------------------------------------
// Cast x: fp32 [4096x1024] -> fp16. Grid 2048.
// ---------------------------------------------------------------------------
__global__ __launch_bounds__(256) void cast_x(
    const float* __restrict__ x, ush* __restrict__ xh) {
  const size_t i = ((size_t)blockIdx.x * 256 + threadIdx.x) * 8;
  float4 a = *(const float4*)&x[i];
  float4 b = *(const float4*)&x[i + 4];
  fragh v;
  v[0] = (_Float16)a.x; v[1] = (_Float16)a.y;
  v[2] = (_Float16)a.z; v[3] = (_Float16)a.w;
  v[4] = (_Float16)b.x; v[5] = (_Float16)b.y;
  v[6] = (_Float16)b.z; v[7] = (_Float16)b.w;
  *(fragh*)&xh[i] = v;
}

// ---------------------------------------------------------------------------
// Fused QKV GEMM, fp16 single-term, 128x128 tile (R7 config -- R8's 6/CU
// TLP experiment regressed), now with COUNTED-VMCNT pipeline (T4): per
// K-step, issue stage(t+1) then s_waitcnt vmcnt(4) -- waits only t's own
// 4 loads, leaving t+1's 4 in flight ACROSS the raw s_barrier. Replaces
// __syncthreads' full drain (the measured ~50% stall: all pipes <25%).
// Safety: each wave waits its own loads pre-barrier (global_load_lds
// per-wave); end barrier protects WAR on buf reuse; unroll 1 pins the
// stage/wait pairing; sched_barrier fences the asm (rule #18).
// Grid (8,32,3) = 768 = 3/CU, LDS 32KB.
// ---------------------------------------------------------------------------
__global__ __launch_bounds__(256) void gemm_qkv(
    const ush* __restrict__ xh,
    const ush* __restrict__ Bq, const ush* __restrict__ Bk,
    const ush* __restrict__ Bv,
    const float* __restrict__ bq, const float* __restrict__ bk,
    const float* __restrict__ bv,
    ush* __restrict__ qh, ush* __restrict__ kh, ush* __restrict__ vT) {
  __shared__ __align__(16) ush As[2][128][32];   // [buf][m][k] fp16 bits
  __shared__ __align__(16) ush Bs[2][128][32];   // [buf][n][k] fp16 bits
  const int tid = threadIdx.x, lane = tid & 63, wave = tid >> 6;
  const int l15 = lane & 15, quad = lane >> 4;
  const int m0 = blockIdx.y * 128, n0 = blockIdx.x * 128;
  const int z = blockIdx.z;
  const ush* Bg = (z == 0) ? Bq : (z == 1) ? Bk : Bv;
  const float* bias = (z == 0) ? bq : (z == 1) ? bk : bv;
  ush* outp = (z == 0) ? qh : (z == 1) ? kh : vT;

  const int wm = (wave >> 1) * 64, wn = (wave & 1) * 64;

  f32x4 acc[4][4];
#pragma unroll
  for (int i = 0; i < 4; i++)
#pragma unroll
    for (int j = 0; j < 4; j++) acc[i][j] = (f32x4){0.f, 0.f, 0.f, 0.f};

  // 4 global_load_lds per wave per stage (A:2 + B:2)
  auto stage = [&](int bi, int k0) {
#pragma unroll
    for (int jj = 0; jj < 2; jj++) {
      const int call = wave * 2 + jj;
      const int c = call * 64 + lane;         // [0,512)
      const int r = c >> 2, ch = c & 3;
      load_lds16(xh + (size_t)(m0 + r) * 1024 + k0 + ch * 8,
                 &As[bi][0][0] + (size_t)call * 512);
    }
#pragma unroll
    for (int jj = 0; jj < 2; jj++) {
      const int call = wave * 2 + jj;
      const int c = call * 64 + lane;
      const int r = c >> 2, ch = c & 3;
      load_lds16(Bg + (size_t)(n0 + r) * 1024 + k0 + ch * 8,
                 &Bs[bi][0][0] + (size_t)call * 512);
    }
  };

  auto compute = [&](int cur) {
    fragh a[4], b[2][2];
#pragma unroll
    for (int s = 0; s < 4; s++)
      a[s] = *(const fragh*)&As[cur][wm + s * 16 + l15][quad * 8];
#pragma unroll
    for (int t = 0; t < 4; t++) {
      fragh bt = *(const fragh*)&Bs[cur][wn + t * 16 + l15][quad * 8];
#pragma unroll
      for (int mi = 0; mi < 4; mi++)
        acc[mi][t] = __builtin_amdgcn_mfma_f32_16x16x32_f16(
            a[mi], bt, acc[mi][t], 0, 0, 0);
    }
    (void)b;
  };

  stage(0, 0);
#pragma unroll 1
  for (int t = 0; t < 31; ++t) {
    const int cur = t & 1;
    stage(cur ^ 1, (t + 1) << 5);
    __builtin_amdgcn_sched_barrier(0);
    asm volatile("s_waitcnt vmcnt(4)" ::: "memory");
    __builtin_amdgcn_sched_barrier(0);
    __builtin_amdgcn_s_barrier();
    compute(cur);
    __builtin_amdgcn_s_barrier();
  }
  __builtin_amdgcn_sched_barrier(0);
  asm volatile("s_waitcnt vmcnt(0)" ::: "memory");
  __builtin_amdgcn_sched_barrier(0);
  __builtin_amdgcn_s_barrier();
  compute(1);

#pragma unroll
  for (int mi = 0; mi < 4; mi++) {
    const int rbase = m0 + wm + mi * 16 + quad * 4;
    const int bb = rbase >> 10, ss = rbase & 1023;
#pragma unroll
    for (int ni = 0; ni < 4; ni++) {
      const int col = n0 + wn + ni * 16 + l15;
      const float bv_ = bias[col];
      const int hidx = col >> 6, d = col & 63;
      if (z == 2) {
        // V: direct-transposed vT [bh][d][s], 4 consecutive s packed
        half4 p4;
        p4[0] = (_Float16)(acc[mi][ni][0] + bv_);
        p4[1] = (_Float16)(acc[mi][ni][1] + bv_);
        p4[2] = (_Float16)(acc[mi][ni][2] + bv_);
        p4[3] = (_Float16)(acc[mi][ni][3] + bv_);
        *(half4*)&outp[((size_t)(bb * NH_ + hidx) * D_ + d) * S_ + ss] = p4;
      } else {
#pragma unroll
        for (int r = 0; r < 4; r++) {
          const size_t o =
              ((size_t)(bb * NH_ + hidx) * S_ + (ss + r)) * D_ + d;
          *(_Float16*)&outp[o] = (_Float16)(acc[mi][ni][r] + bv_);
        }
      }
    }
  }
}

// ---------------------------------------------------------------------------
// O-projection GEMM: fp16 single-term, 128x64 tile, counted-vmcnt pipeline
// (3 loads/wave/stage -> vmcnt(3)). fp32 out + bias + residual.
// LDS 24KB. Grid (16,32) = 512 = 2/CU.
// ---------------------------------------------------------------------------
__global__ __launch_bounds__(256) void gemm_o(
    const ush* __restrict__ ctxh, const ush* __restrict__ Bo,
    const float* __restrict__ bo, const float* __restrict__ resid,
    float* __restrict__ outf) {
  __shared__ __align__(16) ush As[2][128][32];   // [buf][m][k]
  __shared__ __align__(16) ush Bs[2][64][32];    // [buf][n][k]
  const int tid = threadIdx.x, lane = tid & 63, wave = tid >> 6;
  const int l15 = lane & 15, quad = lane >> 4;
  const int m0 = blockIdx.y * 128, n0 = blockIdx.x * 64;
  const int wm = (wave >> 1) * 64, wn = (wave & 1) * 32;

  f32x4 acc[4][2];
#pragma unroll
  for (int i = 0; i < 4; i++)
#pragma unroll
    for (int j = 0; j < 2; j++) acc[i][j] = (f32x4){0.f, 0.f, 0.f, 0.f};

  // 3 global_load_lds per wave per stage (A:2 + B:1)
  auto stage = [&](int bi, int k0) {
#pragma unroll
    for (int jj = 0; jj < 2; jj++) {
      const int call = wave * 2 + jj;
      const int c = call * 64 + lane;
      const int r = c >> 2, ch = c & 3;
      load_lds16(ctxh + (size_t)(m0 + r) * 1024 + k0 + ch * 8,
                 &As[bi][0][0] + (size_t)call * 512);
    }
    {
      const int c = wave * 64 + lane;          // [0,256)
      const int r = c >> 2, ch = c & 3;
      load_lds16(Bo + (size_t)(n0 + r) * 1024 + k0 + ch * 8,
                 &Bs[bi][0][0] + (size_t)wave * 512);
    }
  };

  auto compute = [&](int cur) {
    fragh a[4], b[2];
#pragma unroll
    for (int s = 0; s < 4; s++)
      a[s] = *(const fragh*)&As[cur][wm + s * 16 + l15][quad * 8];
#pragma unroll
    for (int t = 0; t < 2; t++)
      b[t] = *(const fragh*)&Bs[cur][wn + t * 16 + l15][quad * 8];
#pragma unroll
    for (int mi = 0; mi < 4; mi++)
#pragma unroll
      for (int ni = 0; ni < 2; ni++)
        acc[mi][ni] = __builtin_amdgcn_mfma_f32_16x16x32_f16(
            a[mi], b[ni], acc[mi][ni], 0, 0, 0);
  };

  stage(0, 0);
#pragma unroll 1
  for (int t = 0; t < 31; ++t) {
    const int cur = t & 1;
    stage(cur ^ 1, (t + 1) << 5);
    __builtin_amdgcn_sched_barrier(0);
    asm volatile("s_waitcnt vmcnt(3)" ::: "memory");
    __builtin_amdgcn_sched_barrier(0);
    __builtin_amdgcn_s_barrier();
    compute(cur);
    __builtin_amdgcn_s_barrier();
  }
  __builtin_amdgcn_sched_barrier(0);
  asm volatile("s_waitcnt vmcnt(0)" ::: "memory");
  __builtin_amdgcn_sched_barrier(0);
  __builtin_amdgcn_s_barrier();
  compute(1);

#pragma unroll
  for (int mi = 0; mi < 4; mi++) {
    const int rbase = m0 + wm + mi * 16 + quad * 4;
#pragma unroll
    for (int ni = 0; ni < 2; ni++) {
      const int col = n0 + wn + ni * 16 + l15;
      const float bv_ = bo[col];
#pragma unroll
      for (int r = 0; r < 4; r++) {
        const int m = rbase + r;
        outf[(size_t)m * 1024 + col] =
            acc[mi][ni][r] + bv_ + resid[(size_t)m * 1024 + col];
      }
    }
  }
}

// ---------------------------------------------------------------------------
// MFMA flash attention, fp16 (verified R7): window |j0-q0| <= 128, LDS-LUT
// softmax with fixed shift M=2, fp16 P/ctx. LDS ~28KB -> 4 blocks/CU.
// ---------------------------------------------------------------------------
__global__ __launch_bounds__(256) void attn2(
    const ush* __restrict__ qh, const ush* __restrict__ kh,
    const ush* __restrict__ vT, ush* __restrict__ ch) {
  __shared__ __align__(16) ush Kh[64][72];
  __shared__ __align__(16) ush VTs[64][72];   // [d][j]
  __shared__ __align__(16) ush Pst[64][72];   // [m][j]
  __shared__ float LUT[256];
  const int tid = threadIdx.x;
  const int lane = tid & 63, wave = tid >> 6;
  const int l15 = lane & 15, quad = lane >> 4;
  const int w16 = wave * 16;
  const int bh = blockIdx.y;
  const int b = bh >> 4, h = bh & 15;
  const int q0 = blockIdx.x * 64;

  const float K1 = 0.18033688011112042f;   // 0.125 * log2(e)
  const float K2 = 0.14426950408889634f;   // 0.1   * log2(e)
  {
    const float dd = (float)tid;
    LUT[tid] = __expf(-0.1f * fminf(dd, 5.0f)) * K1 - dd * K2
             - 2.8853900817779268f;        // 2*log2(e): fixed shift M=2
  }

  const size_t qrow = ((size_t)bh * S_ + q0 + w16 + l15) * D_;
  fragh a_h[2];
  a_h[0] = *(const fragh*)&qh[qrow + quad * 8];
  a_h[1] = *(const fragh*)&qh[qrow + 32 + quad * 8];

  f32x4 o[4];
  float lrow[4];
#pragma unroll
  for (int i = 0; i < 4; i++) {
    o[i] = (f32x4){0.f, 0.f, 0.f, 0.f};
    lrow[i] = 0.f;
  }

  const size_t kbase = (size_t)bh * S_ * D_;
  const size_t vbase = (size_t)bh * D_ * S_;

  const int jlo = (q0 > 128) ? q0 - 128 : 0;
  const int jend = (q0 + 192 < S_) ? q0 + 192 : S_;

  for (int j0 = jlo; j0 < jend; j0 += 64) {
    __syncthreads();   // prior tile's frag reads done (also fences LUT)
#pragma unroll
    for (int it = 0; it < 2; it++) {
      const int flat = tid + 256 * it;
      const int row = flat >> 3, dc = (flat & 7) * 8;
      *(uint4*)&Kh[row][dc] =
          *(const uint4*)&kh[kbase + (size_t)(j0 + row) * D_ + dc];
      *(uint4*)&VTs[row][dc] =
          *(const uint4*)&vT[vbase + (size_t)row * S_ + j0 + dc];
    }
    __syncthreads();

    // ---- S = Q.K^T (single fp16 term) ----
    f32x4 c4[4];
#pragma unroll
    for (int nt = 0; nt < 4; nt++) c4[nt] = (f32x4){0.f, 0.f, 0.f, 0.f};
#pragma unroll
    for (int kk = 0; kk < 2; kk++) {
#pragma unroll
      for (int nt = 0; nt < 4; nt++) {
        fragh bh_ = *(const fragh*)&Kh[nt * 16 + l15][kk * 32 + quad * 8];
        c4[nt] = __builtin_amdgcn_mfma_f32_16x16x32_f16(a_h[kk], bh_, c4[nt], 0, 0, 0);
      }
    }

    // ---- LUT softmax + P store (C-layout: row=quad*4+r) ----
    const int ib = q0 + w16 + quad * 4 - j0 - l15;
#pragma unroll
    for (int r = 0; r < 4; r++) {
#pragma unroll
      for (int nt = 0; nt < 4; nt++) {
        int di = ib + r - nt * 16;
        di = (di < 0) ? -di : di;
        const float sv = exp2f(fmaf(c4[nt][r], K1, LUT[di]));
        lrow[r] += sv;
        *(_Float16*)&Pst[w16 + quad * 4 + r][nt * 16 + l15] = (_Float16)sv;
      }
    }

    // ---- PV (own rows only; same-wave LDS ordering, no barrier) ----
    fragh pa[2];
    pa[0] = *(const fragh*)&Pst[w16 + l15][quad * 8];
    pa[1] = *(const fragh*)&Pst[w16 + l15][32 + quad * 8];
#pragma unroll
    for (int dt = 0; dt < 4; dt++) {
      fragh vb0 = *(const fragh*)&VTs[dt * 16 + l15][quad * 8];
      fragh vb1 = *(const fragh*)&VTs[dt * 16 + l15][32 + quad * 8];
      o[dt] = __builtin_amdgcn_mfma_f32_16x16x32_f16(pa[0], vb0, o[dt], 0, 0, 0);
      o[dt] = __builtin_amdgcn_mfma_f32_16x16x32_f16(pa[1], vb1, o[dt], 0, 0, 0);
    }
  }

  // ---- deferred row-sum reduction + normalize + write fp16 ctx ----
#pragma unroll
  for (int r = 0; r < 4; r++) {
#pragma unroll
    for (int off = 1; off < 16; off <<= 1) lrow[r] += __shfl_xor(lrow[r], off);
    const float inv = 1.0f / lrow[r];
    const size_t rowp =
        ((size_t)(b * S_ + q0 + w16 + quad * 4 + r)) * H_ + h * 64;
#pragma unroll
    for (int dt = 0; dt < 4; dt++)
      *(_Float16*)&ch[rowp + dt * 16 + l15] = (_Float16)(o[dt][r] * inv);
  }
}

// ---------------------------------------------------------------------------
// Fused LayerNorm + span logits: one block per row. (verified R10)
// ---------------------------------------------------------------------------
__global__ __launch_bounds__(256) void ln_span(
    const float* __restrict__ y, const float* __restrict__ g,
    const float* __restrict__ bta, const float* __restrict__ Wsp,
    const float* __restrict__ bs, float* __restrict__ logits) {
  const int row = blockIdx.x;
  const int tid = threadIdx.x, lane = tid & 63, wave = tid >> 6;
  const float* yr = y + (size_t)row * 1024;
  float vals[4], s = 0.f, s2 = 0.f;
#pragma unroll
  for (int i = 0; i < 4; i++) {
    float t = yr[tid + i * 256];
    vals[i] = t; s += t; s2 += t * t;
  }
#pragma unroll
  for (int off = 32; off; off >>= 1) {
    s += __shfl_xor(s, off);
    s2 += __shfl_xor(s2, off);
  }
  __shared__ float red[8];
  __shared__ float red9[4][12];
  if (lane == 0) { red[wave] = s; red[4 + wave] = s2; }
  __syncthreads();
  s = red[0] + red[1] + red[2] + red[3];
  s2 = red[4] + red[5] + red[6] + red[7];
  const float mu = s * (1.0f / 1024.0f);
  const float var = s2 * (1.0f / 1024.0f) - mu * mu;
  const float inv = rsqrtf(var + 1e-5f);

  float lg[9];
#pragma unroll
  for (int l = 0; l < 9; l++) lg[l] = 0.f;
#pragma unroll
  for (int i = 0; i < 4; i++) {
    const int hh = tid + i * 256;
    const float yn = (vals[i] - mu) * inv * g[hh] + bta[hh];
#pragma unroll
    for (int l = 0; l < 9; l++) lg[l] += yn * Wsp[hh * 9 + l];
  }
#pragma unroll
  for (int l = 0; l < 9; l++) {
#pragma unroll
    for (int off = 32; off; off >>= 1) lg[l] += __shfl_xor(lg[l], off);
  }
  if (lane == 0) {
#pragma unroll
    for (int l = 0; l < 9; l++) red9[wave][l] = lg[l];
  }
  __syncthreads();
  if (tid < 9) {
    logits[(size_t)row * 9 + tid] =
        red9[0][tid] + red9[1][tid] + red9[2][tid] + red9[3][tid] + bs[tid];
  }
}

// ---------------------------------------------------------------------------
// Entity-bias adjustment + FP32 output. One thread per token.
// ---------------------------------------------------------------------------
__global__ __launch_bounds__(256) void final_kernel(
    const float* __restrict__ logits, const float* __restrict__ eb,
    float* __restrict__ out) {
  const int m = blockIdx.x * 256 + threadIdx.x;
  const int i = m & 1023;
  float cur[9];
#pragma unroll
  for (int l = 0; l < 9; l++) cur[l] = logits[(size_t)m * 9 + l];
  if (i > 0) {
    const float* prev = logits + (size_t)(m - 1) * 9;
    int am = 0;
    float best = prev[0];
#pragma unroll
    for (int l = 1; l < 9; l++) {
      float pv = prev[l];
      if (pv > best) { best = pv; am = l; }
    }
    if (am == 1) cur[2] += 2.0f * eb[2];
  }
#pragma unroll
  for (int l = 0; l < 9; l++) out[(size_t)m * 9 + l] = cur[l];
}

// ---------------------------------------------------------------------------
extern "C" void kernel_launch(void* const* d_in, const int* in_sizes, int n_in,
                              void* d_out, int out_size, void* d_ws, size_t ws_size,
                              hipStream_t stream) {
  const float* x    = (const float*)d_in[0];
  const float* Wq   = (const float*)d_in[1];
  const float* bq   = (const float*)d_in[2];
  const float* Wk   = (const float*)d_in[3];
  const float* bk   = (const float*)d_in[4];
  const float* Wv   = (const float*)d_in[5];
  const float* bv   = (const float*)d_in[6];
  const float* Wo   = (const float*)d_in[7];
  const float* bo   = (const float*)d_in[8];
  const float* ln_g = (const float*)d_in[9];
  const float* ln_b = (const float*)d_in[10];
  const float* Ws   = (const float*)d_in[11];
  const float* bs   = (const float*)d_in[12];
  const float* eb   = (const float*)d_in[13];
  float* out = (float*)d_out;
  char* W8 = (char*)d_ws;

  // ---- ws layout (fp16 everywhere; 64 MB envelope) ----
  ush* WoT  = (ush*)(W8 + 0 * MB_);
  ush* WqT  = (ush*)(W8 + 2 * MB_);
  ush* WkT  = (ush*)(W8 + 4 * MB_);
  ush* WvT  = (ush*)(W8 + 6 * MB_);
  ush* xh   = (ush*)(W8 + 8 * MB_);
  ush* qh   = (ush*)(W8 + 16 * MB_);
  ush* kh   = (ush*)(W8 + 24 * MB_);
  ush* vT   = (ush*)(W8 + 32 * MB_);
  ush* ctxh = (ush*)(W8 + 40 * MB_);
  float* y_ws  = (float*)(W8 + 48 * MB_);
  float* lg_ws = (float*)(W8 + 16 * MB_);  // over qh (dead after attn)

  cast_wT4<<<dim3(16, 16, 4), 256, 0, stream>>>(
      Wq, Wk, Wv, Wo, WqT, WkT, WvT, WoT);
  cast_x<<<2048, 256, 0, stream>>>(x, xh);

  // Q+K+V fused: 768 blocks = 3/CU, 32KB LDS, counted-vmcnt pipeline.
  gemm_qkv<<<dim3(8, 32, 3), 256, 0, stream>>>(
      xh, WqT, WkT, WvT, bq, bk, bv, qh, kh, vT);
  attn2<<<dim3(16, 64), 256, 0, stream>>>(qh, kh, vT, ctxh);
  gemm_o<<<dim3(16, 32), 256, 0, stream>>>(ctxh, WoT, bo, x, y_ws);
  ln_span<<<4096, 256, 0, stream>>>(y_ws, ln_g, ln_b, Ws, bs, lg_ws);
  final_kernel<<<16, 256, 0, stream>>>(lg_ws, eb, out);
}